// Round 8
// baseline (143.848 us; speedup 1.0000x reference)
//
#include <hip/hip_runtime.h>

typedef __attribute__((ext_vector_type(8))) short short8;
typedef __attribute__((ext_vector_type(4))) float f32x4;
typedef __attribute__((ext_vector_type(4))) unsigned int u32x4;

#define NS    100000
#define DIM   128
#define BATCH 32
#define SEQ   20
#define NBLK  782              /* ceil(100000 / 128) */
#define NCH   25

__device__ __forceinline__ unsigned int f2bf(float f) {
    unsigned int u = __float_as_uint(f);
    unsigned int r = u + 0x7FFFu + ((u >> 16) & 1u);
    return r >> 16;
}

// K1: normalize pred rows -> bf16 predp[b][32 rows][128]; rows 0..19 only.
__global__ __launch_bounds__(64) void k_prednorm(const float* __restrict__ pred,
                                                 unsigned short* __restrict__ predp) {
    int s = blockIdx.x, b = blockIdx.y;
    int lane = threadIdx.x;
    float2 v = ((const float2*)(pred + (size_t)(b * SEQ + s) * DIM))[lane];
    float ss = v.x * v.x + v.y * v.y;
    #pragma unroll
    for (int d = 1; d < 64; d <<= 1) ss += __shfl_xor(ss, d);
    float sc = 1.0f / fmaxf(sqrtf(ss), 1e-8f);
    unsigned int val = f2bf(v.x * sc) | (f2bf(v.y * sc) << 16);
    ((unsigned int*)(predp + ((size_t)b * 32 + s) * DIM))[lane] = val;
}

// ===================== real K2 (unchanged from round 7) =====================
__global__ __launch_bounds__(512, 2) void k_gemm(const float* __restrict__ song,
                                                 const unsigned short* __restrict__ predp,
                                                 float* __restrict__ sim) {
    const int tid  = threadIdx.x;
    const int lane = tid & 63;
    const int wid  = tid >> 6;
    const int l16  = lane & 15;
    const int g    = lane >> 4;
    const int song0 = blockIdx.x * 128;
    const int bq    = wid * 4;

    __shared__ u32x4 lds_[2048];
    char* const lds = (char*)lds_;

    {
        int gn = song0 + wid * 16 + l16;
        gn = gn < NS ? gn : NS - 1;
        const float* sp = song + (size_t)gn * DIM + g * 8;
        float4 v0[4], v1[4];
        #pragma unroll
        for (int kt = 0; kt < 4; ++kt) {
            v0[kt] = *(const float4*)(sp + kt * 32);
            v1[kt] = *(const float4*)(sp + kt * 32 + 4);
        }
        float ss = 0.f;
        #pragma unroll
        for (int kt = 0; kt < 4; ++kt) {
            ss += v0[kt].x*v0[kt].x + v0[kt].y*v0[kt].y + v0[kt].z*v0[kt].z + v0[kt].w*v0[kt].w;
            ss += v1[kt].x*v1[kt].x + v1[kt].y*v1[kt].y + v1[kt].z*v1[kt].z + v1[kt].w*v1[kt].w;
        }
        ss += __shfl_xor(ss, 16); ss += __shfl_xor(ss, 32);
        float sc = 1.0f / fmaxf(sqrtf(ss), 1e-8f);
        int row = wid * 16 + l16;
        #pragma unroll
        for (int kt = 0; kt < 4; ++kt) {
            u32x4 o;
            o[0] = f2bf(v0[kt].x * sc) | (f2bf(v0[kt].y * sc) << 16);
            o[1] = f2bf(v0[kt].z * sc) | (f2bf(v0[kt].w * sc) << 16);
            o[2] = f2bf(v1[kt].x * sc) | (f2bf(v1[kt].y * sc) << 16);
            o[3] = f2bf(v1[kt].z * sc) | (f2bf(v1[kt].w * sc) << 16);
            *(u32x4*)(lds + row * 256 + (((kt * 4 + g) ^ (row & 7)) << 4)) = o;
        }
    }

    short8 Am[4][4];
    short8 At[4];
    #pragma unroll
    for (int bl = 0; bl < 4; ++bl)
        #pragma unroll
        for (int kt = 0; kt < 4; ++kt)
            Am[bl][kt] = *(const short8*)(predp + ((size_t)(bq + bl) * 32 + l16) * DIM + kt * 32 + g * 8);
    {
        int tb = bq + (l16 >> 2), ts = 16 + (l16 & 3);
        #pragma unroll
        for (int kt = 0; kt < 4; ++kt)
            At[kt] = *(const short8*)(predp + ((size_t)tb * 32 + ts) * DIM + kt * 32 + g * 8);
    }
    __syncthreads();

    #pragma unroll 1
    for (int ch = 0; ch < 4; ++ch) {
        const char* r0 = lds + (ch * 32 + l16) * 256;
        const char* r1 = r0 + 16 * 256;
        short8 B0[4], B1[4];
        #pragma unroll
        for (int kt = 0; kt < 4; ++kt) {
            int po = (((kt * 4 + g) ^ (l16 & 7)) << 4);
            B0[kt] = *(const short8*)(r0 + po);
            B1[kt] = *(const short8*)(r1 + po);
        }
        f32x4 aM[4][2];
        f32x4 aT0 = {0,0,0,0}, aT1 = {0,0,0,0};
        #pragma unroll
        for (int bl = 0; bl < 4; ++bl) { aM[bl][0] = (f32x4){0,0,0,0}; aM[bl][1] = (f32x4){0,0,0,0}; }
        #pragma unroll
        for (int kt = 0; kt < 4; ++kt) {
            #pragma unroll
            for (int bl = 0; bl < 4; ++bl) {
                aM[bl][0] = __builtin_amdgcn_mfma_f32_16x16x32_bf16(Am[bl][kt], B0[kt], aM[bl][0], 0, 0, 0);
                aM[bl][1] = __builtin_amdgcn_mfma_f32_16x16x32_bf16(Am[bl][kt], B1[kt], aM[bl][1], 0, 0, 0);
            }
            aT0 = __builtin_amdgcn_mfma_f32_16x16x32_bf16(At[kt], B0[kt], aT0, 0, 0, 0);
            aT1 = __builtin_amdgcn_mfma_f32_16x16x32_bf16(At[kt], B1[kt], aT1, 0, 0, 0);
        }
        int n = song0 + ch * 32 + (lane & 31);
        bool do_st = (lane < 32) && (n < NS);
        float mt0 = fmaxf(fmaxf(aT0[0], aT0[1]), fmaxf(aT0[2], aT0[3]));
        float mt1 = fmaxf(fmaxf(aT1[0], aT1[1]), fmaxf(aT1[2], aT1[3]));
        #pragma unroll
        for (int bl = 0; bl < 4; ++bl) {
            float m0 = fmaxf(fmaxf(aM[bl][0][0], aM[bl][0][1]), fmaxf(aM[bl][0][2], aM[bl][0][3]));
            float m1 = fmaxf(fmaxf(aM[bl][1][0], aM[bl][1][1]), fmaxf(aM[bl][1][2], aM[bl][1][3]));
            m0 = (g == bl) ? fmaxf(m0, mt0) : m0;
            m1 = (g == bl) ? fmaxf(m1, mt1) : m1;
            m0 = fmaxf(m0, __shfl_xor(m0, 16)); m0 = fmaxf(m0, __shfl_xor(m0, 32));
            m1 = fmaxf(m1, __shfl_xor(m1, 16)); m1 = fmaxf(m1, __shfl_xor(m1, 32));
            float mo = (lane & 16) ? m1 : m0;
            if (do_st) sim[(size_t)(bq + bl) * NS + n] = mo;
        }
    }
}

// ===================== PROBE S: staging only =====================
__global__ __launch_bounds__(512, 2) void p_stage(const float* __restrict__ song,
                                                  const unsigned short* __restrict__ predp,
                                                  float* __restrict__ outp) {
    const int tid  = threadIdx.x;
    const int lane = tid & 63;
    const int wid  = tid >> 6;
    const int l16  = lane & 15;
    const int g    = lane >> 4;
    const int song0 = blockIdx.x * 128;
    const int bq    = wid * 4;

    __shared__ u32x4 lds_[2048];
    char* const lds = (char*)lds_;

    {
        int gn = song0 + wid * 16 + l16;
        gn = gn < NS ? gn : NS - 1;
        const float* sp = song + (size_t)gn * DIM + g * 8;
        float4 v0[4], v1[4];
        #pragma unroll
        for (int kt = 0; kt < 4; ++kt) {
            v0[kt] = *(const float4*)(sp + kt * 32);
            v1[kt] = *(const float4*)(sp + kt * 32 + 4);
        }
        float ss = 0.f;
        #pragma unroll
        for (int kt = 0; kt < 4; ++kt) {
            ss += v0[kt].x*v0[kt].x + v0[kt].y*v0[kt].y + v0[kt].z*v0[kt].z + v0[kt].w*v0[kt].w;
            ss += v1[kt].x*v1[kt].x + v1[kt].y*v1[kt].y + v1[kt].z*v1[kt].z + v1[kt].w*v1[kt].w;
        }
        ss += __shfl_xor(ss, 16); ss += __shfl_xor(ss, 32);
        float sc = 1.0f / fmaxf(sqrtf(ss), 1e-8f);
        int row = wid * 16 + l16;
        #pragma unroll
        for (int kt = 0; kt < 4; ++kt) {
            u32x4 o;
            o[0] = f2bf(v0[kt].x * sc) | (f2bf(v0[kt].y * sc) << 16);
            o[1] = f2bf(v0[kt].z * sc) | (f2bf(v0[kt].w * sc) << 16);
            o[2] = f2bf(v1[kt].x * sc) | (f2bf(v1[kt].y * sc) << 16);
            o[3] = f2bf(v1[kt].z * sc) | (f2bf(v1[kt].w * sc) << 16);
            *(u32x4*)(lds + row * 256 + (((kt * 4 + g) ^ (row & 7)) << 4)) = o;
        }
    }

    short8 Am[4][4];
    short8 At[4];
    #pragma unroll
    for (int bl = 0; bl < 4; ++bl)
        #pragma unroll
        for (int kt = 0; kt < 4; ++kt)
            Am[bl][kt] = *(const short8*)(predp + ((size_t)(bq + bl) * 32 + l16) * DIM + kt * 32 + g * 8);
    {
        int tb = bq + (l16 >> 2), ts = 16 + (l16 & 3);
        #pragma unroll
        for (int kt = 0; kt < 4; ++kt)
            At[kt] = *(const short8*)(predp + ((size_t)tb * 32 + ts) * DIM + kt * 32 + g * 8);
    }
    __syncthreads();

    // fold everything (defeat DCE) and store one float per lane
    unsigned int acc = 0u;
    #pragma unroll
    for (int bl = 0; bl < 4; ++bl)
        #pragma unroll
        for (int kt = 0; kt < 4; ++kt) {
            u32x4 t = *(const u32x4*)&Am[bl][kt];
            acc += t[0] + t[1] + t[2] + t[3];
        }
    #pragma unroll
    for (int kt = 0; kt < 4; ++kt) {
        u32x4 t = *(const u32x4*)&At[kt];
        acc += t[0] + t[1] + t[2] + t[3];
    }
    u32x4 l = *(const u32x4*)(lds + ((tid * 67) & 2047) * 16);
    acc += l[0] + l[1] + l[2] + l[3];
    outp[(size_t)blockIdx.x * 512 + tid] = (float)acc;
}

// ===================== PROBE M: core only (no global loads) =====================
__global__ __launch_bounds__(512, 2) void p_core(float* __restrict__ simx) {
    const int tid  = threadIdx.x;
    const int lane = tid & 63;
    const int wid  = tid >> 6;
    const int l16  = lane & 15;
    const int g    = lane >> 4;
    const int song0 = blockIdx.x * 128;
    const int bq    = wid * 4;

    __shared__ u32x4 lds_[2048];
    char* const lds = (char*)lds_;

    // LDS fill from lane-derived constants (same addresses as real staging)
    {
        int row = wid * 16 + l16;
        #pragma unroll
        for (int kt = 0; kt < 4; ++kt) {
            u32x4 o;
            #pragma unroll
            for (int j = 0; j < 4; ++j)
                o[j] = (((unsigned int)tid * 2654435761u) ^ (kt * 0x9e3779b9u) ^ (j * 0x85ebca6bu)) & 0x3f003f00u;
            *(u32x4*)(lds + row * 256 + (((kt * 4 + g) ^ (row & 7)) << 4)) = o;
        }
    }
    // A-frags from constants
    short8 Am[4][4];
    short8 At[4];
    #pragma unroll
    for (int bl = 0; bl < 4; ++bl)
        #pragma unroll
        for (int kt = 0; kt < 4; ++kt) {
            u32x4 t;
            #pragma unroll
            for (int j = 0; j < 4; ++j)
                t[j] = (((unsigned int)lane * 40503u) ^ (bl * 12289u + kt * 769u + j * 97u)) & 0x3f003f00u;
            Am[bl][kt] = *(const short8*)&t;
        }
    #pragma unroll
    for (int kt = 0; kt < 4; ++kt) {
        u32x4 t;
        #pragma unroll
        for (int j = 0; j < 4; ++j)
            t[j] = (((unsigned int)lane * 48611u) ^ (kt * 1543u + j * 389u)) & 0x3f003f00u;
        At[kt] = *(const short8*)&t;
    }
    __syncthreads();

    #pragma unroll 1
    for (int ch = 0; ch < 4; ++ch) {
        const char* r0 = lds + (ch * 32 + l16) * 256;
        const char* r1 = r0 + 16 * 256;
        short8 B0[4], B1[4];
        #pragma unroll
        for (int kt = 0; kt < 4; ++kt) {
            int po = (((kt * 4 + g) ^ (l16 & 7)) << 4);
            B0[kt] = *(const short8*)(r0 + po);
            B1[kt] = *(const short8*)(r1 + po);
        }
        f32x4 aM[4][2];
        f32x4 aT0 = {0,0,0,0}, aT1 = {0,0,0,0};
        #pragma unroll
        for (int bl = 0; bl < 4; ++bl) { aM[bl][0] = (f32x4){0,0,0,0}; aM[bl][1] = (f32x4){0,0,0,0}; }
        #pragma unroll
        for (int kt = 0; kt < 4; ++kt) {
            #pragma unroll
            for (int bl = 0; bl < 4; ++bl) {
                aM[bl][0] = __builtin_amdgcn_mfma_f32_16x16x32_bf16(Am[bl][kt], B0[kt], aM[bl][0], 0, 0, 0);
                aM[bl][1] = __builtin_amdgcn_mfma_f32_16x16x32_bf16(Am[bl][kt], B1[kt], aM[bl][1], 0, 0, 0);
            }
            aT0 = __builtin_amdgcn_mfma_f32_16x16x32_bf16(At[kt], B0[kt], aT0, 0, 0, 0);
            aT1 = __builtin_amdgcn_mfma_f32_16x16x32_bf16(At[kt], B1[kt], aT1, 0, 0, 0);
        }
        int n = song0 + ch * 32 + (lane & 31);
        bool do_st = (lane < 32) && (n < NS);
        float mt0 = fmaxf(fmaxf(aT0[0], aT0[1]), fmaxf(aT0[2], aT0[3]));
        float mt1 = fmaxf(fmaxf(aT1[0], aT1[1]), fmaxf(aT1[2], aT1[3]));
        #pragma unroll
        for (int bl = 0; bl < 4; ++bl) {
            float m0 = fmaxf(fmaxf(aM[bl][0][0], aM[bl][0][1]), fmaxf(aM[bl][0][2], aM[bl][0][3]));
            float m1 = fmaxf(fmaxf(aM[bl][1][0], aM[bl][1][1]), fmaxf(aM[bl][1][2], aM[bl][1][3]));
            m0 = (g == bl) ? fmaxf(m0, mt0) : m0;
            m1 = (g == bl) ? fmaxf(m1, mt1) : m1;
            m0 = fmaxf(m0, __shfl_xor(m0, 16)); m0 = fmaxf(m0, __shfl_xor(m0, 32));
            m1 = fmaxf(m1, __shfl_xor(m1, 16)); m1 = fmaxf(m1, __shfl_xor(m1, 32));
            float mo = (lane & 16) ? m1 : m0;
            if (do_st) simx[(size_t)(bq + bl) * NS + n] = mo;
        }
    }
}

// ===================== PROBE E: full minus epilogue =====================
__global__ __launch_bounds__(512, 2) void p_noepi(const float* __restrict__ song,
                                                  const unsigned short* __restrict__ predp,
                                                  float* __restrict__ outp) {
    const int tid  = threadIdx.x;
    const int lane = tid & 63;
    const int wid  = tid >> 6;
    const int l16  = lane & 15;
    const int g    = lane >> 4;
    const int song0 = blockIdx.x * 128;
    const int bq    = wid * 4;

    __shared__ u32x4 lds_[2048];
    char* const lds = (char*)lds_;

    {
        int gn = song0 + wid * 16 + l16;
        gn = gn < NS ? gn : NS - 1;
        const float* sp = song + (size_t)gn * DIM + g * 8;
        float4 v0[4], v1[4];
        #pragma unroll
        for (int kt = 0; kt < 4; ++kt) {
            v0[kt] = *(const float4*)(sp + kt * 32);
            v1[kt] = *(const float4*)(sp + kt * 32 + 4);
        }
        float ss = 0.f;
        #pragma unroll
        for (int kt = 0; kt < 4; ++kt) {
            ss += v0[kt].x*v0[kt].x + v0[kt].y*v0[kt].y + v0[kt].z*v0[kt].z + v0[kt].w*v0[kt].w;
            ss += v1[kt].x*v1[kt].x + v1[kt].y*v1[kt].y + v1[kt].z*v1[kt].z + v1[kt].w*v1[kt].w;
        }
        ss += __shfl_xor(ss, 16); ss += __shfl_xor(ss, 32);
        float sc = 1.0f / fmaxf(sqrtf(ss), 1e-8f);
        int row = wid * 16 + l16;
        #pragma unroll
        for (int kt = 0; kt < 4; ++kt) {
            u32x4 o;
            o[0] = f2bf(v0[kt].x * sc) | (f2bf(v0[kt].y * sc) << 16);
            o[1] = f2bf(v0[kt].z * sc) | (f2bf(v0[kt].w * sc) << 16);
            o[2] = f2bf(v1[kt].x * sc) | (f2bf(v1[kt].y * sc) << 16);
            o[3] = f2bf(v1[kt].z * sc) | (f2bf(v1[kt].w * sc) << 16);
            *(u32x4*)(lds + row * 256 + (((kt * 4 + g) ^ (row & 7)) << 4)) = o;
        }
    }

    short8 Am[4][4];
    short8 At[4];
    #pragma unroll
    for (int bl = 0; bl < 4; ++bl)
        #pragma unroll
        for (int kt = 0; kt < 4; ++kt)
            Am[bl][kt] = *(const short8*)(predp + ((size_t)(bq + bl) * 32 + l16) * DIM + kt * 32 + g * 8);
    {
        int tb = bq + (l16 >> 2), ts = 16 + (l16 & 3);
        #pragma unroll
        for (int kt = 0; kt < 4; ++kt)
            At[kt] = *(const short8*)(predp + ((size_t)tb * 32 + ts) * DIM + kt * 32 + g * 8);
    }
    __syncthreads();

    #pragma unroll 1
    for (int ch = 0; ch < 4; ++ch) {
        const char* r0 = lds + (ch * 32 + l16) * 256;
        const char* r1 = r0 + 16 * 256;
        short8 B0[4], B1[4];
        #pragma unroll
        for (int kt = 0; kt < 4; ++kt) {
            int po = (((kt * 4 + g) ^ (l16 & 7)) << 4);
            B0[kt] = *(const short8*)(r0 + po);
            B1[kt] = *(const short8*)(r1 + po);
        }
        f32x4 aM[4][2];
        f32x4 aT0 = {0,0,0,0}, aT1 = {0,0,0,0};
        #pragma unroll
        for (int bl = 0; bl < 4; ++bl) { aM[bl][0] = (f32x4){0,0,0,0}; aM[bl][1] = (f32x4){0,0,0,0}; }
        #pragma unroll
        for (int kt = 0; kt < 4; ++kt) {
            #pragma unroll
            for (int bl = 0; bl < 4; ++bl) {
                aM[bl][0] = __builtin_amdgcn_mfma_f32_16x16x32_bf16(Am[bl][kt], B0[kt], aM[bl][0], 0, 0, 0);
                aM[bl][1] = __builtin_amdgcn_mfma_f32_16x16x32_bf16(Am[bl][kt], B1[kt], aM[bl][1], 0, 0, 0);
            }
            aT0 = __builtin_amdgcn_mfma_f32_16x16x32_bf16(At[kt], B0[kt], aT0, 0, 0, 0);
            aT1 = __builtin_amdgcn_mfma_f32_16x16x32_bf16(At[kt], B1[kt], aT1, 0, 0, 0);
        }
        // fold accs directly (no shuffles) — one store per lane
        float fold = aT0[0] + aT0[1] + aT0[2] + aT0[3] + aT1[0] + aT1[1] + aT1[2] + aT1[3];
        #pragma unroll
        for (int bl = 0; bl < 4; ++bl) {
            fold += aM[bl][0][0] + aM[bl][0][1] + aM[bl][0][2] + aM[bl][0][3];
            fold += aM[bl][1][0] + aM[bl][1][1] + aM[bl][1][2] + aM[bl][1][3];
        }
        outp[(size_t)(blockIdx.x * 4 + ch) * 512 + tid] = fold;
    }
}

// K3: streaming stats
__global__ __launch_bounds__(256) void k_stats(const float* __restrict__ sim,
                                               const float* __restrict__ x_inv,
                                               const float* __restrict__ y,
                                               float* __restrict__ pZ,
                                               float* __restrict__ pY,
                                               float* __restrict__ pU) {
    int c = blockIdx.x, b = blockIdx.y;
    int tid = threadIdx.x;
    size_t base4 = (size_t)b * (NS / 4) + (size_t)c * 1000;
    const float4* s4 = (const float4*)sim + base4;
    const float4* x4 = (const float4*)x_inv + base4;
    const float4* y4 = (const float4*)y + base4;
    float z = 0.f, yy = 0.f, u = 0.f;
    for (int i = tid; i < 1000; i += 256) {
        float4 sv = s4[i], xv = x4[i], yv = y4[i];
        float e0 = __expf(sv.x * xv.x), e1 = __expf(sv.y * xv.y);
        float e2 = __expf(sv.z * xv.z), e3 = __expf(sv.w * xv.w);
        float f0 = __expf(yv.x), f1 = __expf(yv.y);
        float f2 = __expf(yv.z), f3 = __expf(yv.w);
        z  += (e0 + e1) + (e2 + e3);
        yy += (f0 + f1) + (f2 + f3);
        u  += (e0 * f0 + e1 * f1) + (e2 * f2 + e3 * f3);
    }
    #pragma unroll
    for (int d = 1; d < 64; d <<= 1) {
        z += __shfl_xor(z, d); yy += __shfl_xor(yy, d); u += __shfl_xor(u, d);
    }
    __shared__ float sz[4], sy[4], su[4];
    int w = tid >> 6;
    if ((tid & 63) == 0) { sz[w] = z; sy[w] = yy; su[w] = u; }
    __syncthreads();
    if (tid == 0) {
        int o = b * NCH + c;
        pZ[o] = sz[0] + sz[1] + sz[2] + sz[3];
        pY[o] = sy[0] + sy[1] + sy[2] + sy[3];
        pU[o] = su[0] + su[1] + su[2] + su[3];
    }
}

__global__ __launch_bounds__(1024) void k_finish(const float* __restrict__ pZ,
                                                 const float* __restrict__ pY,
                                                 const float* __restrict__ pU,
                                                 float* __restrict__ out) {
    __shared__ float sZ[BATCH * NCH], sY[BATCH * NCH], sU[BATCH * NCH], lb[BATCH];
    int tid = threadIdx.x;
    if (tid < BATCH * NCH) { sZ[tid] = pZ[tid]; sY[tid] = pY[tid]; sU[tid] = pU[tid]; }
    __syncthreads();
    if (tid < BATCH) {
        float Z = 0.f, Y = 0.f, U = 0.f;
        #pragma unroll
        for (int j = 0; j < NCH; ++j) {
            Z += sZ[tid * NCH + j]; Y += sY[tid * NCH + j]; U += sU[tid * NCH + j];
        }
        lb[tid] = logf((float)(NS + 1)) - U / (Y * Z);
    }
    __syncthreads();
    if (tid < 64) {
        float v = (tid < BATCH) ? lb[tid] : 0.f;
        #pragma unroll
        for (int d = 1; d < 64; d <<= 1) v += __shfl_xor(v, d);
        if (tid == 0) out[0] = v * (1.0f / BATCH);
    }
}

extern "C" void kernel_launch(void* const* d_in, const int* in_sizes, int n_in,
                              void* d_out, int out_size, void* d_ws, size_t ws_size,
                              hipStream_t stream) {
    const float* pred  = (const float*)d_in[0];
    const float* song  = (const float*)d_in[1];
    const float* x_inv = (const float*)d_in[2];
    const float* y     = (const float*)d_in[3];
    float* out = (float*)d_out;

    char* ws = (char*)d_ws;
    unsigned short* predp = (unsigned short*)ws;                   // 256 KiB
    float* sim = (float*)(ws + 262144);                            // 12.8 MB (probes scribble here first)
    float* pZ  = (float*)(ws + 262144 + 12800000);
    float* pY  = pZ + BATCH * NCH;
    float* pU  = pY + BATCH * NCH;

    k_prednorm<<<dim3(SEQ, BATCH), 64, 0, stream>>>(pred, predp);
    // ---- probes (outputs overwritten by real k_gemm below) ----
    p_stage<<<NBLK, 512, 0, stream>>>(song, predp, sim);
    p_core<<<NBLK, 512, 0, stream>>>(sim);
    p_noepi<<<NBLK, 512, 0, stream>>>(song, predp, sim);
    // ---- real pipeline ----
    k_gemm<<<NBLK, 512, 0, stream>>>(song, predp, sim);
    k_stats<<<dim3(NCH, BATCH), 256, 0, stream>>>(sim, x_inv, y, pZ, pY, pU);
    k_finish<<<1, 1024, 0, stream>>>(pZ, pY, pU, out);
}

// Round 9
// 89.448 us; speedup vs baseline: 1.6082x; 1.6082x over previous
//
#include <hip/hip_runtime.h>

typedef __attribute__((ext_vector_type(8))) short short8;
typedef __attribute__((ext_vector_type(4))) float f32x4;
typedef __attribute__((ext_vector_type(4))) unsigned int u32x4;

#define NS    100000
#define DIM   128
#define BATCH 32
#define SEQ   20
#define NBLK  782              /* ceil(100000 / 128) */
#define NCH   25               /* 25 chunks x 4000 songs */
#define PLANE ((size_t)BATCH * NS)

__device__ __forceinline__ unsigned int f2bf(float f) {
    unsigned int u = __float_as_uint(f);
    unsigned int r = u + 0x7FFFu + ((u >> 16) & 1u);
    return r >> 16;
}
__device__ __forceinline__ float bfu2f(unsigned int v) { return __uint_as_float(v << 16); }

// K1: normalize pred rows -> bf16 predp[b][32 rows][128]; rows 0..19 only.
__global__ __launch_bounds__(64) void k_prednorm(const float* __restrict__ pred,
                                                 unsigned short* __restrict__ predp) {
    int s = blockIdx.x, b = blockIdx.y;
    int lane = threadIdx.x;
    float2 v = ((const float2*)(pred + (size_t)(b * SEQ + s) * DIM))[lane];
    float ss = v.x * v.x + v.y * v.y;
    #pragma unroll
    for (int d = 1; d < 64; d <<= 1) ss += __shfl_xor(ss, d);
    float sc = 1.0f / fmaxf(sqrtf(ss), 1e-8f);
    unsigned int val = f2bf(v.x * sc) | (f2bf(v.y * sc) << 16);
    ((unsigned int*)(predp + ((size_t)b * 32 + s) * DIM))[lane] = val;
}

// ============ K2: GEMM with 2-plane bf16 epilogue (1 shfl, depth-1 chain) ====
__global__ __launch_bounds__(512, 2) void k_gemm(const float* __restrict__ song,
                                                 const unsigned short* __restrict__ predp,
                                                 unsigned short* __restrict__ simh) {
    const int tid  = threadIdx.x;
    const int lane = tid & 63;
    const int wid  = tid >> 6;
    const int l16  = lane & 15;
    const int g    = lane >> 4;
    const int song0 = blockIdx.x * 128;
    const int bq    = wid * 4;

    __shared__ u32x4 lds_[2048];
    char* const lds = (char*)lds_;

    {   // stage songs: load f32 -> normalize -> bf16 -> swizzled LDS
        int gn = song0 + wid * 16 + l16;
        gn = gn < NS ? gn : NS - 1;
        const float* sp = song + (size_t)gn * DIM + g * 8;
        float4 v0[4], v1[4];
        #pragma unroll
        for (int kt = 0; kt < 4; ++kt) {
            v0[kt] = *(const float4*)(sp + kt * 32);
            v1[kt] = *(const float4*)(sp + kt * 32 + 4);
        }
        float ss = 0.f;
        #pragma unroll
        for (int kt = 0; kt < 4; ++kt) {
            ss += v0[kt].x*v0[kt].x + v0[kt].y*v0[kt].y + v0[kt].z*v0[kt].z + v0[kt].w*v0[kt].w;
            ss += v1[kt].x*v1[kt].x + v1[kt].y*v1[kt].y + v1[kt].z*v1[kt].z + v1[kt].w*v1[kt].w;
        }
        ss += __shfl_xor(ss, 16); ss += __shfl_xor(ss, 32);
        float sc = 1.0f / fmaxf(sqrtf(ss), 1e-8f);
        int row = wid * 16 + l16;
        #pragma unroll
        for (int kt = 0; kt < 4; ++kt) {
            u32x4 o;
            o[0] = f2bf(v0[kt].x * sc) | (f2bf(v0[kt].y * sc) << 16);
            o[1] = f2bf(v0[kt].z * sc) | (f2bf(v0[kt].w * sc) << 16);
            o[2] = f2bf(v1[kt].x * sc) | (f2bf(v1[kt].y * sc) << 16);
            o[3] = f2bf(v1[kt].z * sc) | (f2bf(v1[kt].w * sc) << 16);
            *(u32x4*)(lds + row * 256 + (((kt * 4 + g) ^ (row & 7)) << 4)) = o;
        }
    }

    short8 Am[4][4];
    short8 At[4];
    #pragma unroll
    for (int bl = 0; bl < 4; ++bl)
        #pragma unroll
        for (int kt = 0; kt < 4; ++kt)
            Am[bl][kt] = *(const short8*)(predp + ((size_t)(bq + bl) * 32 + l16) * DIM + kt * 32 + g * 8);
    {
        int tb = bq + (l16 >> 2), ts = 16 + (l16 & 3);
        #pragma unroll
        for (int kt = 0; kt < 4; ++kt)
            At[kt] = *(const short8*)(predp + ((size_t)tb * 32 + ts) * DIM + kt * 32 + g * 8);
    }
    __syncthreads();

    #pragma unroll 1
    for (int ch = 0; ch < 4; ++ch) {
        const char* r0 = lds + (ch * 32 + l16) * 256;
        const char* r1 = r0 + 16 * 256;
        short8 B0[4], B1[4];
        #pragma unroll
        for (int kt = 0; kt < 4; ++kt) {
            int po = (((kt * 4 + g) ^ (l16 & 7)) << 4);
            B0[kt] = *(const short8*)(r0 + po);
            B1[kt] = *(const short8*)(r1 + po);
        }
        f32x4 aM[4][2];
        f32x4 aT[2];
        #pragma unroll
        for (int bl = 0; bl < 4; ++bl) { aM[bl][0] = (f32x4){0,0,0,0}; aM[bl][1] = (f32x4){0,0,0,0}; }
        aT[0] = (f32x4){0,0,0,0}; aT[1] = (f32x4){0,0,0,0};
        #pragma unroll
        for (int kt = 0; kt < 4; ++kt) {
            #pragma unroll
            for (int bl = 0; bl < 4; ++bl) {
                aM[bl][0] = __builtin_amdgcn_mfma_f32_16x16x32_bf16(Am[bl][kt], B0[kt], aM[bl][0], 0, 0, 0);
                aM[bl][1] = __builtin_amdgcn_mfma_f32_16x16x32_bf16(Am[bl][kt], B1[kt], aM[bl][1], 0, 0, 0);
            }
            aT[0] = __builtin_amdgcn_mfma_f32_16x16x32_bf16(At[kt], B0[kt], aT[0], 0, 0, 0);
            aT[1] = __builtin_amdgcn_mfma_f32_16x16x32_bf16(At[kt], B1[kt], aT[1], 0, 0, 0);
        }
        // epilogue: per (t,bl): in-lane fmax -> tail fold (g==bl) -> 1 shfl -> plane store
        int nbase = song0 + ch * 32;
        #pragma unroll
        for (int t = 0; t < 2; ++t) {
            float tpm = fmaxf(fmaxf(aT[t][0], aT[t][1]), fmaxf(aT[t][2], aT[t][3]));
            int n = nbase + t * 16 + l16;
            bool do_st = (lane < 32) && (n < NS);
            #pragma unroll
            for (int bl = 0; bl < 4; ++bl) {
                float pm = fmaxf(fmaxf(aM[bl][t][0], aM[bl][t][1]),
                                 fmaxf(aM[bl][t][2], aM[bl][t][3]));
                pm = (g == bl) ? fmaxf(pm, tpm) : pm;
                pm = fmaxf(pm, __shfl_xor(pm, 32));   // pairs g 0<->2, 1<->3
                if (do_st)
                    simh[((size_t)g * BATCH + (bq + bl)) * (size_t)NS + n] =
                        (unsigned short)f2bf(pm);
            }
        }
    }
}

// ============ PROBE: identical core, global loads replaced by hashes ========
__global__ __launch_bounds__(512, 2) void p_core(unsigned short* __restrict__ simh) {
    const int tid  = threadIdx.x;
    const int lane = tid & 63;
    const int wid  = tid >> 6;
    const int l16  = lane & 15;
    const int g    = lane >> 4;
    const int song0 = blockIdx.x * 128;
    const int bq    = wid * 4;

    __shared__ u32x4 lds_[2048];
    char* const lds = (char*)lds_;

    {   // songs from hash (no global loads), same normalize + LDS path
        float4 v0[4], v1[4];
        #pragma unroll
        for (int kt = 0; kt < 4; ++kt) {
            unsigned int h = (unsigned int)tid * 2654435761u + kt * 0x9e3779b9u;
            v0[kt] = (float4){__uint_as_float(0x3f800000u | ((h * 3u) >> 9)),
                              __uint_as_float(0x3f800000u | ((h * 5u) >> 9)),
                              __uint_as_float(0x3f800000u | ((h * 7u) >> 9)),
                              __uint_as_float(0x3f800000u | ((h * 11u) >> 9))};
            v1[kt] = (float4){__uint_as_float(0x3f800000u | ((h * 13u) >> 9)),
                              __uint_as_float(0x3f800000u | ((h * 17u) >> 9)),
                              __uint_as_float(0x3f800000u | ((h * 19u) >> 9)),
                              __uint_as_float(0x3f800000u | ((h * 23u) >> 9))};
        }
        float ss = 0.f;
        #pragma unroll
        for (int kt = 0; kt < 4; ++kt) {
            ss += v0[kt].x*v0[kt].x + v0[kt].y*v0[kt].y + v0[kt].z*v0[kt].z + v0[kt].w*v0[kt].w;
            ss += v1[kt].x*v1[kt].x + v1[kt].y*v1[kt].y + v1[kt].z*v1[kt].z + v1[kt].w*v1[kt].w;
        }
        ss += __shfl_xor(ss, 16); ss += __shfl_xor(ss, 32);
        float sc = 1.0f / fmaxf(sqrtf(ss), 1e-8f);
        int row = wid * 16 + l16;
        #pragma unroll
        for (int kt = 0; kt < 4; ++kt) {
            u32x4 o;
            o[0] = f2bf(v0[kt].x * sc) | (f2bf(v0[kt].y * sc) << 16);
            o[1] = f2bf(v0[kt].z * sc) | (f2bf(v0[kt].w * sc) << 16);
            o[2] = f2bf(v1[kt].x * sc) | (f2bf(v1[kt].y * sc) << 16);
            o[3] = f2bf(v1[kt].z * sc) | (f2bf(v1[kt].w * sc) << 16);
            *(u32x4*)(lds + row * 256 + (((kt * 4 + g) ^ (row & 7)) << 4)) = o;
        }
    }

    short8 Am[4][4];
    short8 At[4];
    #pragma unroll
    for (int bl = 0; bl < 4; ++bl)
        #pragma unroll
        for (int kt = 0; kt < 4; ++kt) {
            u32x4 tv;
            #pragma unroll
            for (int j = 0; j < 4; ++j)
                tv[j] = (((unsigned int)lane * 40503u) ^ (bl * 12289u + kt * 769u + j * 97u)) & 0x3f003f00u;
            Am[bl][kt] = *(const short8*)&tv;
        }
    #pragma unroll
    for (int kt = 0; kt < 4; ++kt) {
        u32x4 tv;
        #pragma unroll
        for (int j = 0; j < 4; ++j)
            tv[j] = (((unsigned int)lane * 48611u) ^ (kt * 1543u + j * 389u)) & 0x3f003f00u;
        At[kt] = *(const short8*)&tv;
    }
    __syncthreads();

    #pragma unroll 1
    for (int ch = 0; ch < 4; ++ch) {
        const char* r0 = lds + (ch * 32 + l16) * 256;
        const char* r1 = r0 + 16 * 256;
        short8 B0[4], B1[4];
        #pragma unroll
        for (int kt = 0; kt < 4; ++kt) {
            int po = (((kt * 4 + g) ^ (l16 & 7)) << 4);
            B0[kt] = *(const short8*)(r0 + po);
            B1[kt] = *(const short8*)(r1 + po);
        }
        f32x4 aM[4][2];
        f32x4 aT[2];
        #pragma unroll
        for (int bl = 0; bl < 4; ++bl) { aM[bl][0] = (f32x4){0,0,0,0}; aM[bl][1] = (f32x4){0,0,0,0}; }
        aT[0] = (f32x4){0,0,0,0}; aT[1] = (f32x4){0,0,0,0};
        #pragma unroll
        for (int kt = 0; kt < 4; ++kt) {
            #pragma unroll
            for (int bl = 0; bl < 4; ++bl) {
                aM[bl][0] = __builtin_amdgcn_mfma_f32_16x16x32_bf16(Am[bl][kt], B0[kt], aM[bl][0], 0, 0, 0);
                aM[bl][1] = __builtin_amdgcn_mfma_f32_16x16x32_bf16(Am[bl][kt], B1[kt], aM[bl][1], 0, 0, 0);
            }
            aT[0] = __builtin_amdgcn_mfma_f32_16x16x32_bf16(At[kt], B0[kt], aT[0], 0, 0, 0);
            aT[1] = __builtin_amdgcn_mfma_f32_16x16x32_bf16(At[kt], B1[kt], aT[1], 0, 0, 0);
        }
        int nbase = song0 + ch * 32;
        #pragma unroll
        for (int t = 0; t < 2; ++t) {
            float tpm = fmaxf(fmaxf(aT[t][0], aT[t][1]), fmaxf(aT[t][2], aT[t][3]));
            int n = nbase + t * 16 + l16;
            bool do_st = (lane < 32) && (n < NS);
            #pragma unroll
            for (int bl = 0; bl < 4; ++bl) {
                float pm = fmaxf(fmaxf(aM[bl][t][0], aM[bl][t][1]),
                                 fmaxf(aM[bl][t][2], aM[bl][t][3]));
                pm = (g == bl) ? fmaxf(pm, tpm) : pm;
                pm = fmaxf(pm, __shfl_xor(pm, 32));
                if (do_st)
                    simh[((size_t)g * BATCH + (bq + bl)) * (size_t)NS + n] =
                        (unsigned short)f2bf(pm);
            }
        }
    }
}

// K3: streaming stats over 2 bf16 planes: s = max(p0,p1); Z,Y,U sums.
__global__ __launch_bounds__(256) void k_stats(const unsigned short* __restrict__ simh,
                                               const float* __restrict__ x_inv,
                                               const float* __restrict__ y,
                                               float* __restrict__ pZ,
                                               float* __restrict__ pY,
                                               float* __restrict__ pU) {
    int c = blockIdx.x, b = blockIdx.y;
    int tid = threadIdx.x;
    size_t nb = (size_t)b * NS + (size_t)c * 4000;
    const unsigned short* P0 = simh + nb;
    const unsigned short* P1 = simh + PLANE + nb;
    const float4* x4 = (const float4*)(x_inv + nb);
    const float4* y4 = (const float4*)(y + nb);
    float z = 0.f, yy = 0.f, u = 0.f;
    for (int i = tid; i < 500; i += 256) {     // 8 songs per iter
        u32x4 a0 = *(const u32x4*)(P0 + (size_t)i * 8);
        u32x4 a1 = *(const u32x4*)(P1 + (size_t)i * 8);
        float4 xv0 = x4[i * 2], xv1 = x4[i * 2 + 1];
        float4 yv0 = y4[i * 2], yv1 = y4[i * 2 + 1];
        float s0 = fmaxf(bfu2f(a0[0] & 0xFFFFu) * 0.f + __uint_as_float((a0[0] & 0xFFFFu) << 16),
                         __uint_as_float((a1[0] & 0xFFFFu) << 16));
        // unpack helper-free explicit form for all 8:
        float sA[8], xA[8], yA[8];
        #pragma unroll
        for (int j = 0; j < 4; ++j) {
            unsigned int w0 = a0[j], w1 = a1[j];
            sA[2*j]   = fmaxf(__uint_as_float(w0 << 16), __uint_as_float(w1 << 16));
            sA[2*j+1] = fmaxf(__uint_as_float(w0 & 0xFFFF0000u), __uint_as_float(w1 & 0xFFFF0000u));
        }
        xA[0]=xv0.x; xA[1]=xv0.y; xA[2]=xv0.z; xA[3]=xv0.w;
        xA[4]=xv1.x; xA[5]=xv1.y; xA[6]=xv1.z; xA[7]=xv1.w;
        yA[0]=yv0.x; yA[1]=yv0.y; yA[2]=yv0.z; yA[3]=yv0.w;
        yA[4]=yv1.x; yA[5]=yv1.y; yA[6]=yv1.z; yA[7]=yv1.w;
        (void)s0;
        #pragma unroll
        for (int j = 0; j < 8; ++j) {
            float e = __expf(sA[j] * xA[j]);
            float f = __expf(yA[j]);
            z += e; yy += f; u += e * f;
        }
    }
    #pragma unroll
    for (int d = 1; d < 64; d <<= 1) {
        z += __shfl_xor(z, d); yy += __shfl_xor(yy, d); u += __shfl_xor(u, d);
    }
    __shared__ float sz[4], sy[4], su[4];
    int w = tid >> 6;
    if ((tid & 63) == 0) { sz[w] = z; sy[w] = yy; su[w] = u; }
    __syncthreads();
    if (tid == 0) {
        int o = b * NCH + c;
        pZ[o] = sz[0] + sz[1] + sz[2] + sz[3];
        pY[o] = sy[0] + sy[1] + sy[2] + sy[3];
        pU[o] = su[0] + su[1] + su[2] + su[3];
    }
}

// K4: combine 800 partials -> per-b loss -> mean
__global__ __launch_bounds__(1024) void k_finish(const float* __restrict__ pZ,
                                                 const float* __restrict__ pY,
                                                 const float* __restrict__ pU,
                                                 float* __restrict__ out) {
    __shared__ float sZ[BATCH * NCH], sY[BATCH * NCH], sU[BATCH * NCH], lb[BATCH];
    int tid = threadIdx.x;
    if (tid < BATCH * NCH) { sZ[tid] = pZ[tid]; sY[tid] = pY[tid]; sU[tid] = pU[tid]; }
    __syncthreads();
    if (tid < BATCH) {
        float Z = 0.f, Y = 0.f, U = 0.f;
        #pragma unroll
        for (int j = 0; j < NCH; ++j) {
            Z += sZ[tid * NCH + j]; Y += sY[tid * NCH + j]; U += sU[tid * NCH + j];
        }
        lb[tid] = logf((float)(NS + 1)) - U / (Y * Z);
    }
    __syncthreads();
    if (tid < 64) {
        float v = (tid < BATCH) ? lb[tid] : 0.f;
        #pragma unroll
        for (int d = 1; d < 64; d <<= 1) v += __shfl_xor(v, d);
        if (tid == 0) out[0] = v * (1.0f / BATCH);
    }
}

extern "C" void kernel_launch(void* const* d_in, const int* in_sizes, int n_in,
                              void* d_out, int out_size, void* d_ws, size_t ws_size,
                              hipStream_t stream) {
    const float* pred  = (const float*)d_in[0];
    const float* song  = (const float*)d_in[1];
    const float* x_inv = (const float*)d_in[2];
    const float* y     = (const float*)d_in[3];
    float* out = (float*)d_out;

    char* ws = (char*)d_ws;
    unsigned short* predp = (unsigned short*)ws;                   // 256 KiB
    unsigned short* simh  = (unsigned short*)(ws + 262144);        // 2 planes bf16 = 12.8 MB
    float* pZ  = (float*)(ws + 262144 + 12800000);
    float* pY  = pZ + BATCH * NCH;
    float* pU  = pY + BATCH * NCH;

    k_prednorm<<<dim3(SEQ, BATCH), 64, 0, stream>>>(pred, predp);
    p_core<<<NBLK, 512, 0, stream>>>(simh);                        // probe (overwritten)
    k_gemm<<<NBLK, 512, 0, stream>>>(song, predp, simh);
    k_stats<<<dim3(NCH, BATCH), 256, 0, stream>>>(simh, x_inv, y, pZ, pY, pU);
    k_finish<<<1, 1024, 0, stream>>>(pZ, pY, pU, out);
}

// Round 10
// 67.081 us; speedup vs baseline: 2.1444x; 1.3334x over previous
//
#include <hip/hip_runtime.h>

typedef __attribute__((ext_vector_type(8))) short short8;
typedef __attribute__((ext_vector_type(4))) float f32x4;
typedef __attribute__((ext_vector_type(4))) unsigned int u32x4;

#define NS    100000
#define NSP   100096           /* padded song rows */
#define DIM   128
#define BATCH 32
#define SEQ   20
#define NBLK  782              /* ceil(100000 / 128) */
#define NCH   25
#define PLANE ((size_t)BATCH * NS)

typedef const __attribute__((address_space(1))) unsigned int g_u32;
typedef __attribute__((address_space(3))) unsigned int l_u32;

__device__ __forceinline__ unsigned int f2bf(float f) {
    unsigned int u = __float_as_uint(f);
    unsigned int r = u + 0x7FFFu + ((u >> 16) & 1u);
    return r >> 16;
}

// K1: normalize pred rows -> bf16 predp[b][32 rows][128]; rows 20..23 zeroed.
__global__ __launch_bounds__(64) void k_prednorm(const float* __restrict__ pred,
                                                 unsigned short* __restrict__ predp) {
    int s = blockIdx.x, b = blockIdx.y;       // grid (24, 32)
    int lane = threadIdx.x;
    unsigned int val = 0u;
    if (s < SEQ) {
        float2 v = ((const float2*)(pred + (size_t)(b * SEQ + s) * DIM))[lane];
        float ss = v.x * v.x + v.y * v.y;
        #pragma unroll
        for (int d = 1; d < 64; d <<= 1) ss += __shfl_xor(ss, d);
        float sc = 1.0f / fmaxf(sqrtf(ss), 1e-8f);
        val = f2bf(v.x * sc) | (f2bf(v.y * sc) << 16);
    }
    ((unsigned int*)(predp + ((size_t)b * 32 + s) * DIM))[lane] = val;
}

// K1b: normalize songs -> bf16 songn[NSP][128] (pad rows zero). Pure stream.
__global__ __launch_bounds__(256) void k_songnorm(const float* __restrict__ song,
                                                  unsigned int* __restrict__ songn) {
    int row = blockIdx.x * 4 + (threadIdx.x >> 6);
    int lane = threadIdx.x & 63;
    unsigned int val = 0u;
    if (row < NS) {
        float2 v = ((const float2*)(song + (size_t)row * DIM))[lane];
        float ss = v.x * v.x + v.y * v.y;
        #pragma unroll
        for (int d = 1; d < 64; d <<= 1) ss += __shfl_xor(ss, d);
        float sc = 1.0f / fmaxf(sqrtf(ss), 1e-8f);
        val = f2bf(v.x * sc) | (f2bf(v.y * sc) << 16);
    }
    songn[(size_t)row * 64 + lane] = val;
}

// K2: high-occupancy GEMM. 8 waves x 2 b's = 16 b; grid (782, 2).
// B staged via global_load_lds (linear dest, pre-swizzled src). One barrier.
__global__ __launch_bounds__(512, 4) void k_gemm(const unsigned short* __restrict__ songn,
                                                 const unsigned short* __restrict__ predp,
                                                 unsigned short* __restrict__ simh) {
    const int tid  = threadIdx.x;
    const int lane = tid & 63;
    const int wid  = tid >> 6;
    const int l16  = lane & 15;
    const int g    = lane >> 4;
    const int song0 = blockIdx.x * 128;
    const int bq    = blockIdx.y * 16 + wid * 2;

    __shared__ char lds[32768];

    // ---- stage B tile: 128 songs x 256B, swizzled-by-source ----
    {
        int r = tid >> 2, q = tid & 3;
        const char* srow = (const char*)songn + (size_t)(song0 + r) * 256;
        int qx = (q ^ ((r >> 1) & 3)) << 2;
        #pragma unroll
        for (int i = 0; i < 4; ++i)
            __builtin_amdgcn_global_load_lds((g_u32*)(srow + ((qx | i) << 4)),
                                             (l_u32*)(lds + i * 8192 + tid * 16),
                                             16, 0, 0);
    }

    // ---- A fragments: 2 main tiles + packed-tail tile (L2-hot) ----
    short8 Am[2][4];
    short8 At[4];
    #pragma unroll
    for (int bl = 0; bl < 2; ++bl)
        #pragma unroll
        for (int kt = 0; kt < 4; ++kt)
            Am[bl][kt] = *(const short8*)(predp + ((size_t)(bq + bl) * 32 + l16) * DIM + kt * 32 + g * 8);
    {
        // tail tile row l16: rows 0..7 -> b=bq+(l16>>2), s=16+(l16&3); rows 8..15 -> zeroed rows 20..23
        int tb = bq + ((l16 >> 2) & 1);
        int ts = 16 + (l16 & 3) + ((l16 & 8) ? 4 : 0);
        #pragma unroll
        for (int kt = 0; kt < 4; ++kt)
            At[kt] = *(const short8*)(predp + ((size_t)tb * 32 + ts) * DIM + kt * 32 + g * 8);
    }
    __syncthreads();                    // the ONLY barrier

    // ---- 4 chunks of 32 songs ----
    #pragma unroll 1
    for (int ch = 0; ch < 4; ++ch) {
        int r0 = ch * 32 + l16, r1 = r0 + 16;
        short8 B0[4], B1[4];
        #pragma unroll
        for (int kt = 0; kt < 4; ++kt) {
            B0[kt] = *(const short8*)(lds + g * 8192 + r0 * 64 + ((kt ^ ((r0 >> 1) & 3)) << 4));
            B1[kt] = *(const short8*)(lds + g * 8192 + r1 * 64 + ((kt ^ ((r1 >> 1) & 3)) << 4));
        }
        f32x4 aM[2][2];
        f32x4 aT[2];
        aM[0][0] = (f32x4){0,0,0,0}; aM[0][1] = (f32x4){0,0,0,0};
        aM[1][0] = (f32x4){0,0,0,0}; aM[1][1] = (f32x4){0,0,0,0};
        aT[0] = (f32x4){0,0,0,0};    aT[1] = (f32x4){0,0,0,0};
        #pragma unroll
        for (int kt = 0; kt < 4; ++kt) {
            aM[0][0] = __builtin_amdgcn_mfma_f32_16x16x32_bf16(Am[0][kt], B0[kt], aM[0][0], 0, 0, 0);
            aM[0][1] = __builtin_amdgcn_mfma_f32_16x16x32_bf16(Am[0][kt], B1[kt], aM[0][1], 0, 0, 0);
            aM[1][0] = __builtin_amdgcn_mfma_f32_16x16x32_bf16(Am[1][kt], B0[kt], aM[1][0], 0, 0, 0);
            aM[1][1] = __builtin_amdgcn_mfma_f32_16x16x32_bf16(Am[1][kt], B1[kt], aM[1][1], 0, 0, 0);
            aT[0]    = __builtin_amdgcn_mfma_f32_16x16x32_bf16(At[kt], B0[kt], aT[0], 0, 0, 0);
            aT[1]    = __builtin_amdgcn_mfma_f32_16x16x32_bf16(At[kt], B1[kt], aT[1], 0, 0, 0);
        }
        // ---- epilogue: 2-plane bf16, 1 shfl, depth-1 chain ----
        int nbase = song0 + ch * 32;
        #pragma unroll
        for (int t = 0; t < 2; ++t) {
            float tpm = fmaxf(fmaxf(aT[t][0], aT[t][1]), fmaxf(aT[t][2], aT[t][3]));
            int n = nbase + t * 16 + l16;
            bool do_st = (lane < 32) && (n < NS);
            #pragma unroll
            for (int bl = 0; bl < 2; ++bl) {
                float pm = fmaxf(fmaxf(aM[bl][t][0], aM[bl][t][1]),
                                 fmaxf(aM[bl][t][2], aM[bl][t][3]));
                pm = (g == bl) ? fmaxf(pm, tpm) : pm;
                pm = fmaxf(pm, __shfl_xor(pm, 32));   // g 0<->2, 1<->3
                if (do_st)
                    simh[((size_t)g * BATCH + (bq + bl)) * (size_t)NS + n] =
                        (unsigned short)f2bf(pm);
            }
        }
    }
}

// K3: streaming stats over 2 bf16 planes: s = max(p0,p1); Z,Y,U sums.
__global__ __launch_bounds__(256) void k_stats(const unsigned short* __restrict__ simh,
                                               const float* __restrict__ x_inv,
                                               const float* __restrict__ y,
                                               float* __restrict__ pZ,
                                               float* __restrict__ pY,
                                               float* __restrict__ pU) {
    int c = blockIdx.x, b = blockIdx.y;
    int tid = threadIdx.x;
    size_t nb = (size_t)b * NS + (size_t)c * 4000;
    const unsigned short* P0 = simh + nb;
    const unsigned short* P1 = simh + PLANE + nb;
    const float4* x4 = (const float4*)(x_inv + nb);
    const float4* y4 = (const float4*)(y + nb);
    float z = 0.f, yy = 0.f, u = 0.f;
    for (int i = tid; i < 500; i += 256) {     // 8 songs per iter
        u32x4 a0 = *(const u32x4*)(P0 + (size_t)i * 8);
        u32x4 a1 = *(const u32x4*)(P1 + (size_t)i * 8);
        float4 xv0 = x4[i * 2], xv1 = x4[i * 2 + 1];
        float4 yv0 = y4[i * 2], yv1 = y4[i * 2 + 1];
        float sA[8], xA[8], yA[8];
        #pragma unroll
        for (int j = 0; j < 4; ++j) {
            unsigned int w0 = a0[j], w1 = a1[j];
            sA[2*j]   = fmaxf(__uint_as_float(w0 << 16), __uint_as_float(w1 << 16));
            sA[2*j+1] = fmaxf(__uint_as_float(w0 & 0xFFFF0000u), __uint_as_float(w1 & 0xFFFF0000u));
        }
        xA[0]=xv0.x; xA[1]=xv0.y; xA[2]=xv0.z; xA[3]=xv0.w;
        xA[4]=xv1.x; xA[5]=xv1.y; xA[6]=xv1.z; xA[7]=xv1.w;
        yA[0]=yv0.x; yA[1]=yv0.y; yA[2]=yv0.z; yA[3]=yv0.w;
        yA[4]=yv1.x; yA[5]=yv1.y; yA[6]=yv1.z; yA[7]=yv1.w;
        #pragma unroll
        for (int j = 0; j < 8; ++j) {
            float e = __expf(sA[j] * xA[j]);
            float f = __expf(yA[j]);
            z += e; yy += f; u += e * f;
        }
    }
    #pragma unroll
    for (int d = 1; d < 64; d <<= 1) {
        z += __shfl_xor(z, d); yy += __shfl_xor(yy, d); u += __shfl_xor(u, d);
    }
    __shared__ float sz[4], sy[4], su[4];
    int w = tid >> 6;
    if ((tid & 63) == 0) { sz[w] = z; sy[w] = yy; su[w] = u; }
    __syncthreads();
    if (tid == 0) {
        int o = b * NCH + c;
        pZ[o] = sz[0] + sz[1] + sz[2] + sz[3];
        pY[o] = sy[0] + sy[1] + sy[2] + sy[3];
        pU[o] = su[0] + su[1] + su[2] + su[3];
    }
}

// K4: combine 800 partials -> per-b loss -> mean
__global__ __launch_bounds__(1024) void k_finish(const float* __restrict__ pZ,
                                                 const float* __restrict__ pY,
                                                 const float* __restrict__ pU,
                                                 float* __restrict__ out) {
    __shared__ float sZ[BATCH * NCH], sY[BATCH * NCH], sU[BATCH * NCH], lb[BATCH];
    int tid = threadIdx.x;
    if (tid < BATCH * NCH) { sZ[tid] = pZ[tid]; sY[tid] = pY[tid]; sU[tid] = pU[tid]; }
    __syncthreads();
    if (tid < BATCH) {
        float Z = 0.f, Y = 0.f, U = 0.f;
        #pragma unroll
        for (int j = 0; j < NCH; ++j) {
            Z += sZ[tid * NCH + j]; Y += sY[tid * NCH + j]; U += sU[tid * NCH + j];
        }
        lb[tid] = logf((float)(NS + 1)) - U / (Y * Z);
    }
    __syncthreads();
    if (tid < 64) {
        float v = (tid < BATCH) ? lb[tid] : 0.f;
        #pragma unroll
        for (int d = 1; d < 64; d <<= 1) v += __shfl_xor(v, d);
        if (tid == 0) out[0] = v * (1.0f / BATCH);
    }
}

extern "C" void kernel_launch(void* const* d_in, const int* in_sizes, int n_in,
                              void* d_out, int out_size, void* d_ws, size_t ws_size,
                              hipStream_t stream) {
    const float* pred  = (const float*)d_in[0];
    const float* song  = (const float*)d_in[1];
    const float* x_inv = (const float*)d_in[2];
    const float* y     = (const float*)d_in[3];
    float* out = (float*)d_out;

    char* ws = (char*)d_ws;
    unsigned short* predp = (unsigned short*)ws;                         // 256 KiB
    unsigned int*   songn = (unsigned int*)(ws + 262144);                // 25.6 MB
    unsigned short* simh  = (unsigned short*)(ws + 262144 + (size_t)NSP * 256);  // 12.8 MB
    float* pZ = (float*)(ws + 262144 + (size_t)NSP * 256 + 12800000);
    float* pY = pZ + BATCH * NCH;
    float* pU = pY + BATCH * NCH;

    k_prednorm<<<dim3(24, BATCH), 64, 0, stream>>>(pred, predp);
    k_songnorm<<<NSP / 4, 256, 0, stream>>>(song, songn);
    k_gemm<<<dim3(NBLK, 2), 512, 0, stream>>>((const unsigned short*)songn, predp, simh);
    k_stats<<<dim3(NCH, BATCH), 256, 0, stream>>>(simh, x_inv, y, pZ, pY, pU);
    k_finish<<<1, 1024, 0, stream>>>(pZ, pY, pU, out);
}